// Round 1
// baseline (4420.095 us; speedup 1.0000x reference)
//
#include <hip/hip_runtime.h>
#include <cstdint>

// LSTM LM: logits = LSTM(E[idx] @ Wi) @ Wo + bo
// B=16, S=256, D=256, H=512, 4H=2048, V=50257 (padded to 50304 = 393*128)
//
// Pipeline:
//  k0_wot   : Wo [512][50257] f32 -> WoTP [50304][512] u32 (packed hi/lo bf16, transposed)
//  k0b_whlo : Wh -> per-(wg,ntile,kstep,lane) bf16-lo B-fragments (global, coalesced)
//  k1_xz    : xz[s][b][g] = (E[idx] @ Wi) fp32 exact
//  k2_lstm  : 64 persistent WGs x 1 wave; split-bf16 MFMA recurrence; atomic barrier/step
//  k3_logits: 128x128-tile split-bf16 3-pass MFMA GEMM + bo, masked store

typedef __attribute__((ext_vector_type(8))) short short8;
typedef __attribute__((ext_vector_type(4))) float f32x4;
typedef __attribute__((ext_vector_type(4))) unsigned int u32x4;

#define DEVFN static __device__ __forceinline__

DEVFN unsigned short f2bf(float f) {
    unsigned int u = __float_as_uint(f);
    return (unsigned short)((u + 0x7FFFu + ((u >> 16) & 1u)) >> 16);  // RNE
}
DEVFN float bf2f(unsigned short h) { return __uint_as_float(((unsigned int)h) << 16); }
DEVFN float sigm(float x) { return 1.0f / (1.0f + __expf(-x)); }
DEVFN float tanh_fast(float x) {
    float e = __expf(-2.0f * fabsf(x));
    float t = (1.0f - e) / (1.0f + e);
    return copysignf(t, x);
}
DEVFN f32x4 fzero() { f32x4 v = {0.f, 0.f, 0.f, 0.f}; return v; }

// ---------------- k0: transpose + split Wo -> WoTP[50304][512] packed u32 ----------------
__global__ __launch_bounds__(256) void k0_wot(const float* __restrict__ Wo,
                                              uint32_t* __restrict__ WoTP) {
    __shared__ float tile[32][33];
    const int bx = blockIdx.x;
    const int cb = bx >> 4;          // 0..1571 (vocab tiles)
    const int kb = bx & 15;          // 0..15   (k tiles)
    const int c0 = cb * 32, k0 = kb * 32;
    const int j = threadIdx.x & 31;
    const int i0 = threadIdx.x >> 5; // 0..7
    for (int ii = i0; ii < 32; ii += 8) {
        const int c = c0 + j;
        tile[ii][j] = (c < 50257) ? Wo[(size_t)(k0 + ii) * 50257 + c] : 0.0f;
    }
    __syncthreads();
    for (int ii = i0; ii < 32; ii += 8) {
        const float v = tile[j][ii];  // Wo[k0+j][c0+ii]
        const unsigned short hi = f2bf(v);
        const unsigned short lo = f2bf(v - bf2f(hi));
        WoTP[(size_t)(c0 + ii) * 512 + k0 + j] = (((unsigned int)hi) << 16) | lo;
    }
}

// ---------------- k0b: Wh bf16-lo B-fragments: [wg][nt][q][lane] 16B each ----------------
__global__ __launch_bounds__(256) void k0b_whlo(const float* __restrict__ Wh,
                                                uint32_t* __restrict__ WLO) {
    const int tid = blockIdx.x * 256 + threadIdx.x;   // 0..131071
    const int lane = tid & 63;
    const int q    = (tid >> 6) & 15;
    const int nt   = (tid >> 10) & 1;
    const int wg   = tid >> 11;
    const int cc   = lane & 15;
    const int gcol = (cc >> 2) * 512 + wg * 8 + nt * 4 + (cc & 3);
    const int kbase = q * 32 + (lane >> 4) * 8;
    u32x4 o;
#pragma unroll
    for (int p = 0; p < 4; ++p) {
        unsigned int pair = 0;
#pragma unroll
        for (int e = 0; e < 2; ++e) {
            const int k = kbase + p * 2 + e;
            const float w = Wh[(size_t)k * 2048 + gcol];
            const unsigned short hi = f2bf(w);
            const unsigned short lo = f2bf(w - bf2f(hi));
            pair |= ((unsigned int)lo) << (e * 16);
        }
        o[p] = pair;
    }
    *(u32x4*)(WLO + (size_t)tid * 4) = o;
}

// ---------------- k1: xz[s][b][g] = sum_d E[idx[b,s],d] * Wi[d,g]  (fp32 exact) ----------
__global__ __launch_bounds__(256) void k1_xz(const int* __restrict__ idx,
                                             const float* __restrict__ E,
                                             const float* __restrict__ Wi,
                                             float* __restrict__ xz) {
    __shared__ float xs[16][256];
    const int s = blockIdx.x;
    const int t = threadIdx.x;
#pragma unroll
    for (int b = 0; b < 16; ++b) {
        const int row = idx[b * 256 + s];
        xs[b][t] = E[(size_t)row * 256 + t];
    }
    __syncthreads();
    for (int half = 0; half < 2; ++half) {
        const int g0 = half * 1024 + t * 4;
        f32x4 acc[16];
#pragma unroll
        for (int b = 0; b < 16; ++b) acc[b] = fzero();
        for (int d = 0; d < 256; ++d) {
            const f32x4 w = *(const f32x4*)&Wi[(size_t)d * 2048 + g0];
#pragma unroll
            for (int b = 0; b < 16; ++b) {
                const float xv = xs[b][d];
                acc[b] += xv * w;
            }
        }
#pragma unroll
        for (int b = 0; b < 16; ++b)
            *(f32x4*)&xz[((size_t)s * 16 + b) * 2048 + g0] = acc[b];
    }
}

// ---------------- k2: persistent LSTM recurrence --------------------------------------
// 64 WGs x 64 threads (1 wave). WG wg owns hidden units j = wg*8 .. wg*8+7.
// 32 Wh columns (4 gates x 8 j), split over 2 ntiles of 16 cols: ntile nt holds
// (gate g, jj = nt*4 + 0..3) at frag-col c = g*4 + (c&3).
// Wh-hi staged in LDS [32][512] bf16, XOR-swizzled; Wh-lo read from WLO frags (global).
// h shared as packed (hi<<16|lo) u32 in hsP[(b*256+t)*512+j]; one atomic barrier per step.
__global__ __launch_bounds__(64) void k2_lstm(const float* __restrict__ Wh,
                                              const float* __restrict__ bh,
                                              const float* __restrict__ xz,
                                              const short8* __restrict__ WLO8,
                                              uint32_t* __restrict__ hsP,
                                              const uint32_t* __restrict__ zeroh,
                                              uint32_t* __restrict__ ctr) {
    __shared__ unsigned short whh[32][512];
    const int wg = blockIdx.x;
    const int lane = threadIdx.x;
    const int c = lane & 15;
    const int qtr = lane >> 4;

    // stage Wh-hi slice (swizzled): thread covers (l = col 0..31, khalf)
    {
        const int l = lane >> 1, kh = lane & 1;
        const int cc = l & 15, nt = l >> 4;
        const int gcol = (cc >> 2) * 512 + wg * 8 + nt * 4 + (cc & 3);
        for (int k8 = kh * 256; k8 < kh * 256 + 256; k8 += 8) {
            short8 v;
#pragma unroll
            for (int i = 0; i < 8; ++i)
                v[i] = (short)f2bf(Wh[(size_t)(k8 + i) * 2048 + gcol]);
            const int slot = (k8 >> 3) ^ (l & 7);
            *(short8*)((char*)whh + l * 1024 + slot * 16) = v;
        }
    }
    __syncthreads();

    int gc[2];
    float bh_v[2];
#pragma unroll
    for (int nt = 0; nt < 2; ++nt) {
        gc[nt] = (c >> 2) * 512 + wg * 8 + nt * 4 + (c & 3);
        bh_v[nt] = bh[gc[nt]];
    }

    float cst[2][4];
#pragma unroll
    for (int nt = 0; nt < 2; ++nt)
#pragma unroll
        for (int r = 0; r < 4; ++r) cst[nt][r] = 0.0f;

    for (int t = 0; t < 256; ++t) {
        // prefetch xz terms for this step (independent of h)
        float xzv[2][4];
#pragma unroll
        for (int nt = 0; nt < 2; ++nt)
#pragma unroll
            for (int r = 0; r < 4; ++r)
                xzv[nt][r] = xz[((size_t)t * 16 + qtr * 4 + r) * 2048 + gc[nt]];

        const uint32_t* hbase = (t == 0)
            ? (zeroh + (size_t)(lane & 15) * 512)
            : (hsP + ((size_t)(lane & 15) * 256 + (t - 1)) * 512);

        f32x4 acc[2][2];  // [ntile][k-parity] -> 4 independent MFMA dep-chains
#pragma unroll
        for (int nt = 0; nt < 2; ++nt) { acc[nt][0] = fzero(); acc[nt][1] = fzero(); }

#pragma unroll
        for (int q = 0; q < 16; ++q) {
            const int kb = q * 32 + qtr * 8;
            const u32x4 h0 = *(const u32x4*)(hbase + kb);
            const u32x4 h1 = *(const u32x4*)(hbase + kb + 4);
            short8 ahi, alo;
#pragma unroll
            for (int i = 0; i < 4; ++i) {
                ahi[i]     = (short)(h0[i] >> 16); alo[i]     = (short)(h0[i] & 0xffffu);
                ahi[4 + i] = (short)(h1[i] >> 16); alo[4 + i] = (short)(h1[i] & 0xffffu);
            }
#pragma unroll
            for (int nt = 0; nt < 2; ++nt) {
                const int l = nt * 16 + c;
                const short8 bhi = *(const short8*)((const char*)whh + l * 1024 +
                                                    (((q * 4 + qtr) ^ (l & 7)) << 4));
                const short8 blo = WLO8[(((size_t)wg * 2 + nt) * 16 + q) * 64 + lane];
                f32x4 a = acc[nt][q & 1];
                a = __builtin_amdgcn_mfma_f32_16x16x32_bf16(ahi, bhi, a, 0, 0, 0);
                a = __builtin_amdgcn_mfma_f32_16x16x32_bf16(ahi, blo, a, 0, 0, 0);
                a = __builtin_amdgcn_mfma_f32_16x16x32_bf16(alo, bhi, a, 0, 0, 0);
                acc[nt][q & 1] = a;
            }
        }

#pragma unroll
        for (int nt = 0; nt < 2; ++nt) {
            f32x4 z4 = acc[nt][0] + acc[nt][1];
#pragma unroll
            for (int r = 0; r < 4; ++r) z4[r] += xzv[nt][r] + bh_v[nt];
#pragma unroll
            for (int r = 0; r < 4; ++r) {
                const int sb = (lane & 0x33);
                const float zi = __shfl(z4[r], sb);
                const float zf = __shfl(z4[r], sb | 4);
                const float zg = __shfl(z4[r], sb | 8);
                const float zo = __shfl(z4[r], sb | 12);
                const float iv = sigm(zi), fv = sigm(zf);
                const float gv = tanh_fast(zg), ov = sigm(zo);
                const float cv = fv * cst[nt][r] + iv * gv;
                cst[nt][r] = cv;
                const float hv = ov * tanh_fast(cv);
                if ((c >> 2) == 0) {  // gate-0 lanes write h (one owner per (b,jj))
                    const unsigned short hi = f2bf(hv);
                    const unsigned short lo = f2bf(hv - bf2f(hi));
                    hsP[((size_t)(qtr * 4 + r) * 256 + t) * 512 + wg * 8 + nt * 4 + c] =
                        (((unsigned int)hi) << 16) | lo;
                }
            }
        }

        if (t < 255) {
            if (lane == 0)
                __hip_atomic_fetch_add(ctr, 1u, __ATOMIC_ACQ_REL, __HIP_MEMORY_SCOPE_AGENT);
            const unsigned int target = 64u * (unsigned int)(t + 1);
            while (__hip_atomic_load(ctr, __ATOMIC_ACQUIRE, __HIP_MEMORY_SCOPE_AGENT) < target)
                __builtin_amdgcn_s_sleep(2);
        }
    }
}

// ---------------- k3: logits = hs @ Wo + bo  (split-bf16 3-pass, 128x128 tiles) --------
__global__ __launch_bounds__(256, 2) void k3_logits(const uint32_t* __restrict__ hsP,
                                                    const uint32_t* __restrict__ WoTP,
                                                    const float* __restrict__ bo,
                                                    float* __restrict__ out) {
    __shared__ unsigned short Ah[128][64];
    __shared__ unsigned short Al[128][64];
    __shared__ unsigned short Bh[128][64];
    __shared__ unsigned short Bl[128][64];

    const int bx = blockIdx.x;
    const int n = bx >> 5;   // 0..392
    const int m = bx & 31;   // 0..31
    const int tid = threadIdx.x;
    const int lane = tid & 63;
    const int wv = tid >> 6;
    const int wr = wv >> 1, wc = wv & 1;

    f32x4 acc[4][4];
#pragma unroll
    for (int i = 0; i < 4; ++i)
#pragma unroll
        for (int j = 0; j < 4; ++j) acc[i][j] = fzero();

    const int srow = tid >> 1, shalf = tid & 1;

    for (int kb = 0; kb < 8; ++kb) {
        __syncthreads();
        {
            const uint32_t* sa = hsP + (size_t)(m * 128 + srow) * 512 + kb * 64 + shalf * 32;
            const uint32_t* sbp = WoTP + (size_t)(n * 128 + srow) * 512 + kb * 64 + shalf * 32;
#pragma unroll
            for (int g = 0; g < 4; ++g) {
                const u32x4 p0 = *(const u32x4*)(sa + g * 8);
                const u32x4 p1 = *(const u32x4*)(sa + g * 8 + 4);
                short8 hi, lo;
#pragma unroll
                for (int i = 0; i < 4; ++i) {
                    hi[i]     = (short)(p0[i] >> 16); lo[i]     = (short)(p0[i] & 0xffffu);
                    hi[4 + i] = (short)(p1[i] >> 16); lo[4 + i] = (short)(p1[i] & 0xffffu);
                }
                const int sw = ((shalf * 4 + g) ^ (srow & 7)) << 4;
                *(short8*)((char*)Ah + srow * 128 + sw) = hi;
                *(short8*)((char*)Al + srow * 128 + sw) = lo;
            }
#pragma unroll
            for (int g = 0; g < 4; ++g) {
                const u32x4 p0 = *(const u32x4*)(sbp + g * 8);
                const u32x4 p1 = *(const u32x4*)(sbp + g * 8 + 4);
                short8 hi, lo;
#pragma unroll
                for (int i = 0; i < 4; ++i) {
                    hi[i]     = (short)(p0[i] >> 16); lo[i]     = (short)(p0[i] & 0xffffu);
                    hi[4 + i] = (short)(p1[i] >> 16); lo[4 + i] = (short)(p1[i] & 0xffffu);
                }
                const int sw = ((shalf * 4 + g) ^ (srow & 7)) << 4;
                *(short8*)((char*)Bh + srow * 128 + sw) = hi;
                *(short8*)((char*)Bl + srow * 128 + sw) = lo;
            }
        }
        __syncthreads();

#pragma unroll
        for (int q = 0; q < 2; ++q) {
            short8 afh[4], afl[4], bfh[4], bfl[4];
#pragma unroll
            for (int mi = 0; mi < 4; ++mi) {
                const int r = wr * 64 + mi * 16 + (lane & 15);
                const int sw = ((q * 4 + (lane >> 4)) ^ (r & 7)) << 4;
                afh[mi] = *(const short8*)((const char*)Ah + r * 128 + sw);
                afl[mi] = *(const short8*)((const char*)Al + r * 128 + sw);
            }
#pragma unroll
            for (int nj = 0; nj < 4; ++nj) {
                const int r = wc * 64 + nj * 16 + (lane & 15);
                const int sw = ((q * 4 + (lane >> 4)) ^ (r & 7)) << 4;
                bfh[nj] = *(const short8*)((const char*)Bh + r * 128 + sw);
                bfl[nj] = *(const short8*)((const char*)Bl + r * 128 + sw);
            }
#pragma unroll
            for (int mi = 0; mi < 4; ++mi)
#pragma unroll
                for (int nj = 0; nj < 4; ++nj) {
                    f32x4 a = acc[mi][nj];
                    a = __builtin_amdgcn_mfma_f32_16x16x32_bf16(afh[mi], bfh[nj], a, 0, 0, 0);
                    a = __builtin_amdgcn_mfma_f32_16x16x32_bf16(afh[mi], bfl[nj], a, 0, 0, 0);
                    a = __builtin_amdgcn_mfma_f32_16x16x32_bf16(afl[mi], bfh[nj], a, 0, 0, 0);
                    acc[mi][nj] = a;
                }
        }
    }

#pragma unroll
    for (int nj = 0; nj < 4; ++nj) {
        const int colg = n * 128 + wc * 64 + nj * 16 + (lane & 15);
        if (colg < 50257) {
            const float bov = bo[colg];
#pragma unroll
            for (int mi = 0; mi < 4; ++mi)
#pragma unroll
                for (int r = 0; r < 4; ++r) {
                    const int rowg = m * 128 + wr * 64 + mi * 16 + (lane >> 4) * 4 + r;
                    out[(size_t)rowg * 50257 + colg] = acc[mi][nj][r] + bov;
                }
        }
    }
}

// ---------------- launch ----------------------------------------------------------------
#define XZ_OFF   0ull           // 256*16*2048*4      = 33,554,432
#define HSP_OFF  33554432ull    // 4096*512*4         =  8,388,608
#define ZERO_OFF 41943040ull    // 16*512*4           =     32,768
#define CTR_OFF  41975808ull    // 256
#define WLO_OFF  41976064ull    // 64*2*16*64*16      =  2,097,152
#define WOT_OFF  44073216ull    // 50304*512*4        = 103,022,592  -> total ~147 MB

extern "C" void kernel_launch(void* const* d_in, const int* in_sizes, int n_in,
                              void* d_out, int out_size, void* d_ws, size_t ws_size,
                              hipStream_t stream) {
    (void)in_sizes; (void)n_in; (void)out_size; (void)ws_size;
    const int*   idx = (const int*)  d_in[0];
    const float* E   = (const float*)d_in[1];
    const float* Wi  = (const float*)d_in[2];
    const float* Wh  = (const float*)d_in[3];
    const float* bh  = (const float*)d_in[4];
    const float* Wo  = (const float*)d_in[5];
    const float* bo  = (const float*)d_in[6];
    float* out = (float*)d_out;
    char* ws = (char*)d_ws;

    float*    xz    = (float*)   (ws + XZ_OFF);
    uint32_t* hsP   = (uint32_t*)(ws + HSP_OFF);
    uint32_t* zeroh = (uint32_t*)(ws + ZERO_OFF);
    uint32_t* ctr   = (uint32_t*)(ws + CTR_OFF);
    uint32_t* WLO   = (uint32_t*)(ws + WLO_OFF);
    uint32_t* WoTP  = (uint32_t*)(ws + WOT_OFF);

    // zero the h(-1) block + barrier counter (contiguous region)
    hipMemsetAsync(ws + ZERO_OFF, 0, 33024, stream);

    hipLaunchKernelGGL(k0_wot,   dim3(25152), dim3(256), 0, stream, Wo, WoTP);
    hipLaunchKernelGGL(k0b_whlo, dim3(512),   dim3(256), 0, stream, Wh, WLO);
    hipLaunchKernelGGL(k1_xz,    dim3(256),   dim3(256), 0, stream, idx, E, Wi, xz);
    hipLaunchKernelGGL(k2_lstm,  dim3(64),    dim3(64),  0, stream,
                       Wh, bh, xz, (const short8*)WLO, hsP, zeroh, ctr);
    hipLaunchKernelGGL(k3_logits, dim3(12576), dim3(256), 0, stream, hsP, WoTP, bo, out);
}

// Round 2
// 4240.966 us; speedup vs baseline: 1.0422x; 1.0422x over previous
//
#include <hip/hip_runtime.h>
#include <cstdint>

// LSTM LM: logits = LSTM(E[idx] @ Wi) @ Wo + bo
// B=16, S=256, D=256, H=512, 4H=2048, V=50257 (padded to 50304 = 393*128)
//
// Pipeline:
//  k0_wot   : Wo [512][50257] f32 -> WoTP [50304][512] u32 (packed hi/lo bf16, transposed)
//  k0b_whlo : Wh -> per-(wg,ntile,kstep,lane) bf16-lo B-fragments (global, coalesced)
//  k1_xz    : xz[s][b][g] = (E[idx] @ Wi) fp32 exact
//  k2_lstm  : 64 persistent WGs x 1 wave; split-bf16 MFMA recurrence;
//             relaxed sc1 (L2-bypass) flag barrier per step — NO acquire/release
//             cache maintenance (round-1 post-mortem: acq/rel cost 12 us/step)
//  k3_logits: 128x128-tile split-bf16 3-pass MFMA GEMM + bo, masked store

typedef __attribute__((ext_vector_type(8))) short short8;
typedef __attribute__((ext_vector_type(4))) float f32x4;
typedef __attribute__((ext_vector_type(4))) unsigned int u32x4;

#define DEVFN static __device__ __forceinline__

DEVFN unsigned short f2bf(float f) {
    unsigned int u = __float_as_uint(f);
    return (unsigned short)((u + 0x7FFFu + ((u >> 16) & 1u)) >> 16);  // RNE
}
DEVFN float bf2f(unsigned short h) { return __uint_as_float(((unsigned int)h) << 16); }
DEVFN float sigm(float x) { return 1.0f / (1.0f + __expf(-x)); }
DEVFN float tanh_fast(float x) {
    float e = __expf(-2.0f * fabsf(x));
    float t = (1.0f - e) / (1.0f + e);
    return copysignf(t, x);
}
DEVFN f32x4 fzero() { f32x4 v = {0.f, 0.f, 0.f, 0.f}; return v; }

// ---------------- k0: transpose + split Wo -> WoTP[50304][512] packed u32 ----------------
__global__ __launch_bounds__(256) void k0_wot(const float* __restrict__ Wo,
                                              uint32_t* __restrict__ WoTP) {
    __shared__ float tile[32][33];
    const int bx = blockIdx.x;
    const int cb = bx >> 4;          // 0..1571 (vocab tiles)
    const int kb = bx & 15;          // 0..15   (k tiles)
    const int c0 = cb * 32, k0 = kb * 32;
    const int j = threadIdx.x & 31;
    const int i0 = threadIdx.x >> 5; // 0..7
    for (int ii = i0; ii < 32; ii += 8) {
        const int c = c0 + j;
        tile[ii][j] = (c < 50257) ? Wo[(size_t)(k0 + ii) * 50257 + c] : 0.0f;
    }
    __syncthreads();
    for (int ii = i0; ii < 32; ii += 8) {
        const float v = tile[j][ii];  // Wo[k0+j][c0+ii]
        const unsigned short hi = f2bf(v);
        const unsigned short lo = f2bf(v - bf2f(hi));
        WoTP[(size_t)(c0 + ii) * 512 + k0 + j] = (((unsigned int)hi) << 16) | lo;
    }
}

// ---------------- k0b: Wh bf16-lo B-fragments: [wg][nt][q][lane] 16B each ----------------
__global__ __launch_bounds__(256) void k0b_whlo(const float* __restrict__ Wh,
                                                uint32_t* __restrict__ WLO) {
    const int tid = blockIdx.x * 256 + threadIdx.x;   // 0..131071
    const int lane = tid & 63;
    const int q    = (tid >> 6) & 15;
    const int nt   = (tid >> 10) & 1;
    const int wg   = tid >> 11;
    const int cc   = lane & 15;
    const int gcol = (cc >> 2) * 512 + wg * 8 + nt * 4 + (cc & 3);
    const int kbase = q * 32 + (lane >> 4) * 8;
    u32x4 o;
#pragma unroll
    for (int p = 0; p < 4; ++p) {
        unsigned int pair = 0;
#pragma unroll
        for (int e = 0; e < 2; ++e) {
            const int k = kbase + p * 2 + e;
            const float w = Wh[(size_t)k * 2048 + gcol];
            const unsigned short hi = f2bf(w);
            const unsigned short lo = f2bf(w - bf2f(hi));
            pair |= ((unsigned int)lo) << (e * 16);
        }
        o[p] = pair;
    }
    *(u32x4*)(WLO + (size_t)tid * 4) = o;
}

// ---------------- k1: xz[s][b][g] = sum_d E[idx[b,s],d] * Wi[d,g]  (fp32 exact) ----------
__global__ __launch_bounds__(256) void k1_xz(const int* __restrict__ idx,
                                             const float* __restrict__ E,
                                             const float* __restrict__ Wi,
                                             float* __restrict__ xz) {
    __shared__ float xs[16][256];
    const int s = blockIdx.x;
    const int t = threadIdx.x;
#pragma unroll
    for (int b = 0; b < 16; ++b) {
        const int row = idx[b * 256 + s];
        xs[b][t] = E[(size_t)row * 256 + t];
    }
    __syncthreads();
    for (int half = 0; half < 2; ++half) {
        const int g0 = half * 1024 + t * 4;
        f32x4 acc[16];
#pragma unroll
        for (int b = 0; b < 16; ++b) acc[b] = fzero();
        for (int d = 0; d < 256; ++d) {
            const f32x4 w = *(const f32x4*)&Wi[(size_t)d * 2048 + g0];
#pragma unroll
            for (int b = 0; b < 16; ++b) {
                const float xv = xs[b][d];
                acc[b] += xv * w;
            }
        }
#pragma unroll
        for (int b = 0; b < 16; ++b)
            *(f32x4*)&xz[((size_t)s * 16 + b) * 2048 + g0] = acc[b];
    }
}

// ---------------- k2: persistent LSTM recurrence --------------------------------------
// 64 WGs x 64 threads (1 wave). WG wg owns hidden units j = wg*8 .. wg*8+7.
// Sync protocol (all RELAXED — zero cache-maintenance ops):
//   writer: h via sc1 (L2-bypass) relaxed atomic stores -> s_waitcnt vmcnt(0)
//           -> flag[wg]=t+1 via sc1 relaxed store (single writer, no RMW)
//   reader: lane l polls flag[l] (sc1 load) until __all(flag >= t); h read back
//           with sc1 relaxed u64 atomic loads (also kills stale-L2-across-replay).
__global__ __launch_bounds__(64) void k2_lstm(const float* __restrict__ Wh,
                                              const float* __restrict__ bh,
                                              const float* __restrict__ xz,
                                              const short8* __restrict__ WLO8,
                                              uint32_t* __restrict__ hsP,
                                              const uint32_t* __restrict__ zeroh,
                                              uint32_t* __restrict__ flags) {
    __shared__ unsigned short whh[32][512];
    const int wg = blockIdx.x;
    const int lane = threadIdx.x;
    const int c = lane & 15;
    const int qtr = lane >> 4;

    // stage Wh-hi slice (swizzled): thread covers (l = col 0..31, khalf)
    {
        const int l = lane >> 1, kh = lane & 1;
        const int cc = l & 15, nt = l >> 4;
        const int gcol = (cc >> 2) * 512 + wg * 8 + nt * 4 + (cc & 3);
        for (int k8 = kh * 256; k8 < kh * 256 + 256; k8 += 8) {
            short8 v;
#pragma unroll
            for (int i = 0; i < 8; ++i)
                v[i] = (short)f2bf(Wh[(size_t)(k8 + i) * 2048 + gcol]);
            const int slot = (k8 >> 3) ^ (l & 7);
            *(short8*)((char*)whh + l * 1024 + slot * 16) = v;
        }
    }
    __syncthreads();

    int gc[2];
    float bh_v[2];
#pragma unroll
    for (int nt = 0; nt < 2; ++nt) {
        gc[nt] = (c >> 2) * 512 + wg * 8 + nt * 4 + (c & 3);
        bh_v[nt] = bh[gc[nt]];
    }

    float cst[2][4];
#pragma unroll
    for (int nt = 0; nt < 2; ++nt)
#pragma unroll
        for (int r = 0; r < 4; ++r) cst[nt][r] = 0.0f;

    // prefetch xz for step 0
    float xzv[2][4];
#pragma unroll
    for (int nt = 0; nt < 2; ++nt)
#pragma unroll
        for (int r = 0; r < 4; ++r)
            xzv[nt][r] = xz[((size_t)(qtr * 4 + r)) * 2048 + gc[nt]];

    const uint32_t* flg = flags + lane;

    for (int t = 0; t < 256; ++t) {
        // wait for all WGs to have published h(t-1)  (xz(t) loads already in flight)
        if (t > 0) {
            while (true) {
                const uint32_t v = __hip_atomic_load(flg, __ATOMIC_RELAXED,
                                                     __HIP_MEMORY_SCOPE_AGENT);
                if (__all((int)(v >= (uint32_t)t))) break;
            }
            __builtin_amdgcn_sched_barrier(0);
        }

        const uint32_t* hbase = (t == 0)
            ? (zeroh + (size_t)(lane & 15) * 512)
            : (hsP + ((size_t)(lane & 15) * 256 + (t - 1)) * 512);

        f32x4 acc[2][2];  // [ntile][k-parity] -> 4 independent MFMA dep-chains
#pragma unroll
        for (int nt = 0; nt < 2; ++nt) { acc[nt][0] = fzero(); acc[nt][1] = fzero(); }

#pragma unroll
        for (int q = 0; q < 16; ++q) {
            const int kb = q * 32 + qtr * 8;
            const unsigned long long* hb64 = (const unsigned long long*)(hbase + kb);
            unsigned long long d[4];
#pragma unroll
            for (int i = 0; i < 4; ++i)
                d[i] = __hip_atomic_load(hb64 + i, __ATOMIC_RELAXED,
                                         __HIP_MEMORY_SCOPE_AGENT);
            short8 ahi, alo;
#pragma unroll
            for (int i = 0; i < 4; ++i) {
                const uint32_t wlo32 = (uint32_t)d[i];
                const uint32_t whi32 = (uint32_t)(d[i] >> 32);
                ahi[2 * i]     = (short)(wlo32 >> 16); alo[2 * i]     = (short)(wlo32 & 0xffffu);
                ahi[2 * i + 1] = (short)(whi32 >> 16); alo[2 * i + 1] = (short)(whi32 & 0xffffu);
            }
#pragma unroll
            for (int nt = 0; nt < 2; ++nt) {
                const int l = nt * 16 + c;
                const short8 bhi = *(const short8*)((const char*)whh + l * 1024 +
                                                    (((q * 4 + qtr) ^ (l & 7)) << 4));
                const short8 blo = WLO8[(((size_t)wg * 2 + nt) * 16 + q) * 64 + lane];
                f32x4 a = acc[nt][q & 1];
                a = __builtin_amdgcn_mfma_f32_16x16x32_bf16(ahi, bhi, a, 0, 0, 0);
                a = __builtin_amdgcn_mfma_f32_16x16x32_bf16(ahi, blo, a, 0, 0, 0);
                a = __builtin_amdgcn_mfma_f32_16x16x32_bf16(alo, bhi, a, 0, 0, 0);
                acc[nt][q & 1] = a;
            }
        }

#pragma unroll
        for (int nt = 0; nt < 2; ++nt) {
            f32x4 z4 = acc[nt][0] + acc[nt][1];
#pragma unroll
            for (int r = 0; r < 4; ++r) z4[r] += xzv[nt][r] + bh_v[nt];
#pragma unroll
            for (int r = 0; r < 4; ++r) {
                const int sb = (lane & 0x33);
                const float zi = __shfl(z4[r], sb);
                const float zf = __shfl(z4[r], sb | 4);
                const float zg = __shfl(z4[r], sb | 8);
                const float zo = __shfl(z4[r], sb | 12);
                const float iv = sigm(zi), fv = sigm(zf);
                const float gv = tanh_fast(zg), ov = sigm(zo);
                const float cv = fv * cst[nt][r] + iv * gv;
                cst[nt][r] = cv;
                const float hv = ov * tanh_fast(cv);
                if ((c >> 2) == 0) {  // gate-0 lanes write h (one owner per (b,jj))
                    const unsigned short hi = f2bf(hv);
                    const unsigned short lo = f2bf(hv - bf2f(hi));
                    const uint32_t packed = (((uint32_t)hi) << 16) | lo;
                    __hip_atomic_store(
                        &hsP[((size_t)(qtr * 4 + r) * 256 + t) * 512 + wg * 8 + nt * 4 + c],
                        packed, __ATOMIC_RELAXED, __HIP_MEMORY_SCOPE_AGENT);
                }
            }
        }

        // h stores at coherence point before flag becomes visible
        asm volatile("s_waitcnt vmcnt(0)" ::: "memory");
        if (lane == 0)
            __hip_atomic_store(&flags[wg], (uint32_t)(t + 1), __ATOMIC_RELAXED,
                               __HIP_MEMORY_SCOPE_AGENT);

        // prefetch xz for t+1 so its latency hides under the next spin
        if (t < 255) {
#pragma unroll
            for (int nt = 0; nt < 2; ++nt)
#pragma unroll
                for (int r = 0; r < 4; ++r)
                    xzv[nt][r] = xz[((size_t)(t + 1) * 16 + qtr * 4 + r) * 2048 + gc[nt]];
        }
    }
}

// ---------------- k3: logits = hs @ Wo + bo  (split-bf16 3-pass, 128x128 tiles) --------
__global__ __launch_bounds__(256, 2) void k3_logits(const uint32_t* __restrict__ hsP,
                                                    const uint32_t* __restrict__ WoTP,
                                                    const float* __restrict__ bo,
                                                    float* __restrict__ out) {
    __shared__ unsigned short Ah[128][64];
    __shared__ unsigned short Al[128][64];
    __shared__ unsigned short Bh[128][64];
    __shared__ unsigned short Bl[128][64];

    const int bx = blockIdx.x;
    const int n = bx >> 5;   // 0..392
    const int m = bx & 31;   // 0..31
    const int tid = threadIdx.x;
    const int lane = tid & 63;
    const int wv = tid >> 6;
    const int wr = wv >> 1, wc = wv & 1;

    f32x4 acc[4][4];
#pragma unroll
    for (int i = 0; i < 4; ++i)
#pragma unroll
        for (int j = 0; j < 4; ++j) acc[i][j] = fzero();

    const int srow = tid >> 1, shalf = tid & 1;

    for (int kb = 0; kb < 8; ++kb) {
        __syncthreads();
        {
            const uint32_t* sa = hsP + (size_t)(m * 128 + srow) * 512 + kb * 64 + shalf * 32;
            const uint32_t* sbp = WoTP + (size_t)(n * 128 + srow) * 512 + kb * 64 + shalf * 32;
#pragma unroll
            for (int g = 0; g < 4; ++g) {
                const u32x4 p0 = *(const u32x4*)(sa + g * 8);
                const u32x4 p1 = *(const u32x4*)(sa + g * 8 + 4);
                short8 hi, lo;
#pragma unroll
                for (int i = 0; i < 4; ++i) {
                    hi[i]     = (short)(p0[i] >> 16); lo[i]     = (short)(p0[i] & 0xffffu);
                    hi[4 + i] = (short)(p1[i] >> 16); lo[4 + i] = (short)(p1[i] & 0xffffu);
                }
                const int sw = ((shalf * 4 + g) ^ (srow & 7)) << 4;
                *(short8*)((char*)Ah + srow * 128 + sw) = hi;
                *(short8*)((char*)Al + srow * 128 + sw) = lo;
            }
#pragma unroll
            for (int g = 0; g < 4; ++g) {
                const u32x4 p0 = *(const u32x4*)(sbp + g * 8);
                const u32x4 p1 = *(const u32x4*)(sbp + g * 8 + 4);
                short8 hi, lo;
#pragma unroll
                for (int i = 0; i < 4; ++i) {
                    hi[i]     = (short)(p0[i] >> 16); lo[i]     = (short)(p0[i] & 0xffffu);
                    hi[4 + i] = (short)(p1[i] >> 16); lo[4 + i] = (short)(p1[i] & 0xffffu);
                }
                const int sw = ((shalf * 4 + g) ^ (srow & 7)) << 4;
                *(short8*)((char*)Bh + srow * 128 + sw) = hi;
                *(short8*)((char*)Bl + srow * 128 + sw) = lo;
            }
        }
        __syncthreads();

#pragma unroll
        for (int q = 0; q < 2; ++q) {
            short8 afh[4], afl[4], bfh[4], bfl[4];
#pragma unroll
            for (int mi = 0; mi < 4; ++mi) {
                const int r = wr * 64 + mi * 16 + (lane & 15);
                const int sw = ((q * 4 + (lane >> 4)) ^ (r & 7)) << 4;
                afh[mi] = *(const short8*)((const char*)Ah + r * 128 + sw);
                afl[mi] = *(const short8*)((const char*)Al + r * 128 + sw);
            }
#pragma unroll
            for (int nj = 0; nj < 4; ++nj) {
                const int r = wc * 64 + nj * 16 + (lane & 15);
                const int sw = ((q * 4 + (lane >> 4)) ^ (r & 7)) << 4;
                bfh[nj] = *(const short8*)((const char*)Bh + r * 128 + sw);
                bfl[nj] = *(const short8*)((const char*)Bl + r * 128 + sw);
            }
#pragma unroll
            for (int mi = 0; mi < 4; ++mi)
#pragma unroll
                for (int nj = 0; nj < 4; ++nj) {
                    f32x4 a = acc[mi][nj];
                    a = __builtin_amdgcn_mfma_f32_16x16x32_bf16(afh[mi], bfh[nj], a, 0, 0, 0);
                    a = __builtin_amdgcn_mfma_f32_16x16x32_bf16(afh[mi], bfl[nj], a, 0, 0, 0);
                    a = __builtin_amdgcn_mfma_f32_16x16x32_bf16(afl[mi], bfh[nj], a, 0, 0, 0);
                    acc[mi][nj] = a;
                }
        }
    }

#pragma unroll
    for (int nj = 0; nj < 4; ++nj) {
        const int colg = n * 128 + wc * 64 + nj * 16 + (lane & 15);
        if (colg < 50257) {
            const float bov = bo[colg];
#pragma unroll
            for (int mi = 0; mi < 4; ++mi)
#pragma unroll
                for (int r = 0; r < 4; ++r) {
                    const int rowg = m * 128 + wr * 64 + mi * 16 + (lane >> 4) * 4 + r;
                    out[(size_t)rowg * 50257 + colg] = acc[mi][nj][r] + bov;
                }
        }
    }
}

// ---------------- launch ----------------------------------------------------------------
#define XZ_OFF   0ull           // 256*16*2048*4      = 33,554,432
#define HSP_OFF  33554432ull    // 4096*512*4         =  8,388,608
#define ZERO_OFF 41943040ull    // 16*512*4           =     32,768
#define FLG_OFF  41975808ull    // 64*4 = 256
#define WLO_OFF  41976064ull    // 64*2*16*64*16      =  2,097,152
#define WOT_OFF  44073216ull    // 50304*512*4        = 103,022,592  -> total ~147 MB

extern "C" void kernel_launch(void* const* d_in, const int* in_sizes, int n_in,
                              void* d_out, int out_size, void* d_ws, size_t ws_size,
                              hipStream_t stream) {
    (void)in_sizes; (void)n_in; (void)out_size; (void)ws_size;
    const int*   idx = (const int*)  d_in[0];
    const float* E   = (const float*)d_in[1];
    const float* Wi  = (const float*)d_in[2];
    const float* Wh  = (const float*)d_in[3];
    const float* bh  = (const float*)d_in[4];
    const float* Wo  = (const float*)d_in[5];
    const float* bo  = (const float*)d_in[6];
    float* out = (float*)d_out;
    char* ws = (char*)d_ws;

    float*    xz    = (float*)   (ws + XZ_OFF);
    uint32_t* hsP   = (uint32_t*)(ws + HSP_OFF);
    uint32_t* zeroh = (uint32_t*)(ws + ZERO_OFF);
    uint32_t* flags = (uint32_t*)(ws + FLG_OFF);
    uint32_t* WLO   = (uint32_t*)(ws + WLO_OFF);
    uint32_t* WoTP  = (uint32_t*)(ws + WOT_OFF);

    // zero the h(-1) block + flag array (contiguous region)
    hipMemsetAsync(ws + ZERO_OFF, 0, 33024, stream);

    hipLaunchKernelGGL(k0_wot,   dim3(25152), dim3(256), 0, stream, Wo, WoTP);
    hipLaunchKernelGGL(k0b_whlo, dim3(512),   dim3(256), 0, stream, Wh, WLO);
    hipLaunchKernelGGL(k1_xz,    dim3(256),   dim3(256), 0, stream, idx, E, Wi, xz);
    hipLaunchKernelGGL(k2_lstm,  dim3(64),    dim3(64),  0, stream,
                       Wh, bh, xz, (const short8*)WLO, hsP, zeroh, flags);
    hipLaunchKernelGGL(k3_logits, dim3(12576), dim3(256), 0, stream, hsP, WoTP, bo, out);
}